// Round 2
// baseline (241.740 us; speedup 1.0000x reference)
//
#include <hip/hip_runtime.h>

// ReLU over fp32, memory-bound streaming. float4 (16 B/lane), grid-stride
// unrolled x4 for MLP, nontemporal hints (no reuse -> don't allocate caches).
// n = 32*4096*1024 = 134,217,728.

typedef float f4 __attribute__((ext_vector_type(4)));

__device__ __forceinline__ f4 relu4(f4 v) {
    v.x = v.x > 0.0f ? v.x : 0.0f;
    v.y = v.y > 0.0f ? v.y : 0.0f;
    v.z = v.z > 0.0f ? v.z : 0.0f;
    v.w = v.w > 0.0f ? v.w : 0.0f;
    return v;
}

__global__ void __launch_bounds__(256) relu_f4_kernel(const f4* __restrict__ in,
                                                      f4* __restrict__ out,
                                                      long long n4) {
    const long long stride = (long long)gridDim.x * blockDim.x;
    long long i = (long long)blockIdx.x * blockDim.x + threadIdx.x;

    // Main: 4 independent loads in flight per thread.
    for (; i + 3 * stride < n4; i += 4 * stride) {
        f4 a = __builtin_nontemporal_load(in + i);
        f4 b = __builtin_nontemporal_load(in + i + stride);
        f4 c = __builtin_nontemporal_load(in + i + 2 * stride);
        f4 d = __builtin_nontemporal_load(in + i + 3 * stride);
        a = relu4(a);
        b = relu4(b);
        c = relu4(c);
        d = relu4(d);
        __builtin_nontemporal_store(a, out + i);
        __builtin_nontemporal_store(b, out + i + stride);
        __builtin_nontemporal_store(c, out + i + 2 * stride);
        __builtin_nontemporal_store(d, out + i + 3 * stride);
    }
    // Remainder grid-stride iterations.
    for (; i < n4; i += stride) {
        __builtin_nontemporal_store(relu4(__builtin_nontemporal_load(in + i)),
                                    out + i);
    }
}

__global__ void relu_tail_kernel(const float* __restrict__ in,
                                 float* __restrict__ out,
                                 long long start, long long n) {
    long long i = start + (long long)blockIdx.x * blockDim.x + threadIdx.x;
    if (i < n) {
        float v = in[i];
        out[i] = v > 0.0f ? v : 0.0f;
    }
}

extern "C" void kernel_launch(void* const* d_in, const int* in_sizes, int n_in,
                              void* d_out, int out_size, void* d_ws, size_t ws_size,
                              hipStream_t stream) {
    const float* x = (const float*)d_in[0];
    float* y = (float*)d_out;
    long long n = (long long)in_sizes[0];

    long long n4 = n / 4;
    const int block = 256;
    // 2048 blocks = 256 CU x 8 blocks/CU; grid-stride covers the rest.
    long long want = (n4 + block - 1) / block;
    int grid = (int)(want < 2048 ? (want > 0 ? want : 1) : 2048);

    if (n4 > 0) {
        relu_f4_kernel<<<grid, block, 0, stream>>>(
            (const f4*)x, (f4*)y, n4);
    }

    long long tail_start = n4 * 4;
    long long tail = n - tail_start;
    if (tail > 0) {
        int tgrid = (int)((tail + block - 1) / block);
        relu_tail_kernel<<<tgrid, block, 0, stream>>>(x, y, tail_start, n);
    }
}

// Round 3
// 179.067 us; speedup vs baseline: 1.3500x; 1.3500x over previous
//
#include <hip/hip_runtime.h>

// ReLU over fp32, memory-bound streaming. Exact-fit grid: one float4 per
// thread, no loop, 32-bit indexing. n = 32*4096*1024 = 134,217,728 -> n4 =
// 33,554,432 float4s = 131072 blocks of 256.

typedef float f4 __attribute__((ext_vector_type(4)));

__global__ void relu_f4_onepass(const f4* __restrict__ in,
                                f4* __restrict__ out,
                                unsigned n4) {
    unsigned i = blockIdx.x * 256u + threadIdx.x;
    if (i < n4) {
        f4 v = in[i];
        v.x = v.x > 0.0f ? v.x : 0.0f;
        v.y = v.y > 0.0f ? v.y : 0.0f;
        v.z = v.z > 0.0f ? v.z : 0.0f;
        v.w = v.w > 0.0f ? v.w : 0.0f;
        out[i] = v;
    }
}

__global__ void relu_tail_kernel(const float* __restrict__ in,
                                 float* __restrict__ out,
                                 long long start, long long n) {
    long long i = start + (long long)blockIdx.x * blockDim.x + threadIdx.x;
    if (i < n) {
        float v = in[i];
        out[i] = v > 0.0f ? v : 0.0f;
    }
}

extern "C" void kernel_launch(void* const* d_in, const int* in_sizes, int n_in,
                              void* d_out, int out_size, void* d_ws, size_t ws_size,
                              hipStream_t stream) {
    const float* x = (const float*)d_in[0];
    float* y = (float*)d_out;
    long long n = (long long)in_sizes[0];

    long long n4 = n / 4;
    const int block = 256;

    if (n4 > 0) {
        unsigned grid = (unsigned)((n4 + block - 1) / block);
        relu_f4_onepass<<<grid, block, 0, stream>>>(
            (const f4*)x, (f4*)y, (unsigned)n4);
    }

    long long tail_start = n4 * 4;
    long long tail = n - tail_start;
    if (tail > 0) {
        int tgrid = (int)((tail + block - 1) / block);
        relu_tail_kernel<<<tgrid, block, 0, stream>>>(x, y, tail_start, n);
    }
}